// Round 1
// baseline (1145.517 us; speedup 1.0000x reference)
//
#include <hip/hip_runtime.h>
#include <hip/hip_bf16.h>
#include <cstdint>
#include <cstddef>

// Problem constants (fixed by the harness problem instance).
#define MM 8192
#define KK 4096
#define NN 12288

#define BM 128
#define BN 128
#define BK 64   // 64 bf16 = 128 B per LDS row

typedef __bf16 bf16x8 __attribute__((ext_vector_type(8)));
typedef float  f32x4  __attribute__((ext_vector_type(4)));

// fp32 -> bf16 round-to-nearest-even (finite inputs).
__device__ __forceinline__ unsigned short f2bf(float f) {
    union { float f; unsigned int u; } v; v.f = f;
    unsigned int r = v.u + 0x7fffu + ((v.u >> 16) & 1u);
    return (unsigned short)(r >> 16);
}

// async global->LDS, 16 B per lane. LDS dest must be wave-uniform base;
// HW writes base + lane*16. Global src is per-lane.
__device__ __forceinline__ void gload_lds16(const void* g, void* l) {
    __builtin_amdgcn_global_load_lds(
        (__attribute__((address_space(1))) void*)g,
        (__attribute__((address_space(3))) void*)l,
        16, 0, 0);
}

// ---------------- pre-pass 1: input fp32 -> bf16 ----------------
__global__ __launch_bounds__(256) void cvt_a_kernel(
    const float* __restrict__ in, unsigned short* __restrict__ out)
{
    size_t i = (size_t)blockIdx.x * 256 + threadIdx.x;   // 8 elems / thread
    const float4* p = (const float4*)in;
    float4 x = p[2 * i], y = p[2 * i + 1];
    union { unsigned short h[8]; uint4 v; } u;
    u.h[0] = f2bf(x.x); u.h[1] = f2bf(x.y); u.h[2] = f2bf(x.z); u.h[3] = f2bf(x.w);
    u.h[4] = f2bf(y.x); u.h[5] = f2bf(y.y); u.h[6] = f2bf(y.z); u.h[7] = f2bf(y.w);
    ((uint4*)out)[i] = u.v;
}

// ---------------- pre-pass 2: dequant int4 codes -> bf16 [N,K] ----------------
__global__ __launch_bounds__(256) void dq_w_kernel(
    const int* __restrict__ w, const float* __restrict__ snz,
    unsigned short* __restrict__ out)
{
    size_t t = (size_t)blockIdx.x * 256 + threadIdx.x;   // 8 codes / thread
    int kc = (int)(t & (KK / 8 - 1));                    // K/8 = 512
    int n  = (int)(t >> 9);
    int g  = kc >> 2;                                    // 8 codes per thread, 32 per group
    float2 sz = ((const float2*)snz)[(size_t)g * NN + n];  // {scale, zero}
    const int4* wp = (const int4*)w;
    int4 q0 = wp[2 * t], q1 = wp[2 * t + 1];
    union { unsigned short h[8]; uint4 v; } u;
    u.h[0] = f2bf((float)(q0.x - 8) * sz.x + sz.y);
    u.h[1] = f2bf((float)(q0.y - 8) * sz.x + sz.y);
    u.h[2] = f2bf((float)(q0.z - 8) * sz.x + sz.y);
    u.h[3] = f2bf((float)(q0.w - 8) * sz.x + sz.y);
    u.h[4] = f2bf((float)(q1.x - 8) * sz.x + sz.y);
    u.h[5] = f2bf((float)(q1.y - 8) * sz.x + sz.y);
    u.h[6] = f2bf((float)(q1.z - 8) * sz.x + sz.y);
    u.h[7] = f2bf((float)(q1.w - 8) * sz.x + sz.y);
    ((uint4*)out)[t] = u.v;
}

// ---------------- GEMM: C[M,N] = A[M,K] * W[N,K]^T + bias ----------------
// m97 structure: 128x128 tile, BK=64, 4 waves (2x2), 16x16x32 bf16 MFMA,
// global_load_lds width-16 staging, XOR-swizzled LDS chunks (16B chunk index
// XOR'd with row&7) to avoid the 16-way bank conflict of 128-B rows.
// FUSED variant (ws too small): reg-staged fp32->bf16 convert + int4 dequant.
template <bool FUSED>
__global__ __launch_bounds__(256) void gemm_kernel(
    const unsigned short* __restrict__ A,   // bf16 [M,K]   (fast path)
    const unsigned short* __restrict__ Bw,  // bf16 [N,K]   (fast path)
    const float* __restrict__ Af,           // fp32 [M,K]   (fused path)
    const int* __restrict__ Wq,             // int codes [N,K] (fused path)
    const float* __restrict__ snz,          // [K/32][N][2]  (fused path)
    const float* __restrict__ bias,         // [N]
    float* __restrict__ C)                  // fp32 [M,N]
{
    __shared__ alignas(16) unsigned short As[BM * BK];
    __shared__ alignas(16) unsigned short Bs[BN * BK];

    const int tid  = threadIdx.x;
    const int lane = tid & 63;
    const int wave = tid >> 6;

    // XCD-aware swizzle (nwg = 6144, divisible by 8).
    const int NTN = NN / BN;                 // 96
    const int nwg = (MM / BM) * NTN;         // 6144
    const int cpx = nwg >> 3;
    int wg = (blockIdx.x & 7) * cpx + (blockIdx.x >> 3);
    const int tm = wg / NTN;
    const int tn = wg - tm * NTN;

    const int wm = wave >> 1, wn = wave & 1; // 2x2 wave grid, 64x64 each

    f32x4 acc[4][4] = {};

    // ---- staging lane constants (fast path) ----
    // wave w issue i: LDS bytes [w*4096 + i*1024, +1024), lane writes 16 B.
    // row = w*32 + i*8 + (lane>>3), phys chunk = lane&7,
    // stored logical chunk = phys ^ (row&7) = (lane&7) ^ ((lane>>3)&7).
    const int lrow = lane >> 3;
    const int lc   = (lane & 7) ^ (lrow & 7);
    const size_t a_base = (size_t)(tm * BM + wave * 32 + lrow) * KK + lc * 8;
    const size_t b_base = (size_t)(tn * BN + wave * 32 + lrow) * KK + lc * 8;
    char* AsB = (char*)As + wave * 4096;
    char* BsB = (char*)Bs + wave * 4096;

    // ---- compute-side lane constants ----
    // frag read: logical chunk (kk*4 + lane>>4) at row (..+lane&15);
    // row&7 == lane&7, phys byte = row*128 + (chunk ^ (lane&7))*16.
    const int r7  = lane & 7;
    const int pc0 = (((lane >> 4)    ) ^ r7) * 16;
    const int pc1 = (((lane >> 4) + 4) ^ r7) * 16;
    const int arow = wm * 64 + (lane & 15);
    const int brow = wn * 64 + (lane & 15);
    const char* AsR = (const char*)As;
    const char* BsR = (const char*)Bs;

    // ---- fused-path lane constants ----
    const int frow = tid >> 1;     // 0..127
    const int fh   = tid & 1;      // col half (32 bf16 = one quant group)
    const int frx  = frow & 7;

    for (int k0 = 0; k0 < KK; k0 += BK) {
        if constexpr (!FUSED) {
#pragma unroll
            for (int i = 0; i < 4; ++i) {
                gload_lds16(A  + a_base + (size_t)i * 8 * KK + k0, AsB + i * 1024);
                gload_lds16(Bw + b_base + (size_t)i * 8 * KK + k0, BsB + i * 1024);
            }
        } else {
            {   // A: fp32 -> bf16, swizzled ds_write
                const float* ap = Af + (size_t)(tm * BM + frow) * KK + k0 + fh * 32;
#pragma unroll
                for (int c = 0; c < 4; ++c) {
                    float4 x = ((const float4*)ap)[2 * c];
                    float4 y = ((const float4*)ap)[2 * c + 1];
                    union { unsigned short h[8]; uint4 v; } u;
                    u.h[0] = f2bf(x.x); u.h[1] = f2bf(x.y); u.h[2] = f2bf(x.z); u.h[3] = f2bf(x.w);
                    u.h[4] = f2bf(y.x); u.h[5] = f2bf(y.y); u.h[6] = f2bf(y.z); u.h[7] = f2bf(y.w);
                    int lc2 = fh * 4 + c;
                    *(uint4*)&As[frow * 64 + ((lc2 ^ frx) * 8)] = u.v;
                }
            }
            {   // W: dequant int4 codes -> bf16, swizzled ds_write
                const int nrow = tn * BN + frow;
                const int* wp = Wq + (size_t)nrow * KK + k0 + fh * 32;
                float2 sz = ((const float2*)snz)[(size_t)((k0 >> 5) + fh) * NN + nrow];
#pragma unroll
                for (int c = 0; c < 4; ++c) {
                    int4 q0 = ((const int4*)wp)[2 * c];
                    int4 q1 = ((const int4*)wp)[2 * c + 1];
                    union { unsigned short h[8]; uint4 v; } u;
                    u.h[0] = f2bf((float)(q0.x - 8) * sz.x + sz.y);
                    u.h[1] = f2bf((float)(q0.y - 8) * sz.x + sz.y);
                    u.h[2] = f2bf((float)(q0.z - 8) * sz.x + sz.y);
                    u.h[3] = f2bf((float)(q0.w - 8) * sz.x + sz.y);
                    u.h[4] = f2bf((float)(q1.x - 8) * sz.x + sz.y);
                    u.h[5] = f2bf((float)(q1.y - 8) * sz.x + sz.y);
                    u.h[6] = f2bf((float)(q1.z - 8) * sz.x + sz.y);
                    u.h[7] = f2bf((float)(q1.w - 8) * sz.x + sz.y);
                    int lc2 = fh * 4 + c;
                    *(uint4*)&Bs[frow * 64 + ((lc2 ^ frx) * 8)] = u.v;
                }
            }
        }
        __syncthreads();

        // kk = 0 (k0..k0+31)
        {
            bf16x8 af[4], bfr[4];
#pragma unroll
            for (int x = 0; x < 4; ++x) {
                af[x]  = *(const bf16x8*)(AsR + (arow + x * 16) * 128 + pc0);
                bfr[x] = *(const bf16x8*)(BsR + (brow + x * 16) * 128 + pc0);
            }
#pragma unroll
            for (int mi = 0; mi < 4; ++mi)
#pragma unroll
                for (int ni = 0; ni < 4; ++ni)
                    acc[mi][ni] = __builtin_amdgcn_mfma_f32_16x16x32_bf16(
                        af[mi], bfr[ni], acc[mi][ni], 0, 0, 0);
        }
        // kk = 1 (k0+32..k0+63)
        {
            bf16x8 af[4], bfr[4];
#pragma unroll
            for (int x = 0; x < 4; ++x) {
                af[x]  = *(const bf16x8*)(AsR + (arow + x * 16) * 128 + pc1);
                bfr[x] = *(const bf16x8*)(BsR + (brow + x * 16) * 128 + pc1);
            }
#pragma unroll
            for (int mi = 0; mi < 4; ++mi)
#pragma unroll
                for (int ni = 0; ni < 4; ++ni)
                    acc[mi][ni] = __builtin_amdgcn_mfma_f32_16x16x32_bf16(
                        af[mi], bfr[ni], acc[mi][ni], 0, 0, 0);
        }
        __syncthreads();
    }

    // Epilogue: C/D layout col = lane&15, row = (lane>>4)*4 + j. Fuse bias.
    const int crow = tm * BM + wm * 64 + (lane >> 4) * 4;
    const int ccol = tn * BN + wn * 64 + (lane & 15);
    float bv[4];
#pragma unroll
    for (int ni = 0; ni < 4; ++ni) bv[ni] = bias[ccol + ni * 16];
#pragma unroll
    for (int mi = 0; mi < 4; ++mi)
#pragma unroll
        for (int ni = 0; ni < 4; ++ni)
#pragma unroll
            for (int j = 0; j < 4; ++j)
                C[(size_t)(crow + mi * 16 + j) * NN + ccol + ni * 16] =
                    acc[mi][ni][j] + bv[ni];
}

extern "C" void kernel_launch(void* const* d_in, const int* in_sizes, int n_in,
                              void* d_out, int out_size, void* d_ws, size_t ws_size,
                              hipStream_t stream)
{
    const float* inA  = (const float*)d_in[0];   // [M,K] fp32
    const int*   Wq   = (const int*)d_in[1];     // [N,K] int codes
    const float* snz  = (const float*)d_in[2];   // [K/32,N,2] fp32
    const float* bias = (const float*)d_in[3];   // [N] fp32
    float* out = (float*)d_out;

    const size_t needA = (size_t)MM * KK * 2;
    const size_t needW = (size_t)NN * KK * 2;
    const int grid = (MM / BM) * (NN / BN);      // 6144

    if (ws_size >= needA + needW) {
        unsigned short* Abf = (unsigned short*)d_ws;
        unsigned short* Wbf = (unsigned short*)((char*)d_ws + needA);
        cvt_a_kernel<<<(MM * KK / 8) / 256, 256, 0, stream>>>(inA, Abf);
        dq_w_kernel<<<(NN * KK / 8) / 256, 256, 0, stream>>>(Wq, snz, Wbf);
        gemm_kernel<false><<<grid, 256, 0, stream>>>(
            Abf, Wbf, nullptr, nullptr, nullptr, bias, out);
    } else {
        gemm_kernel<true><<<grid, 256, 0, stream>>>(
            nullptr, nullptr, inA, Wq, snz, bias, out);
    }
}

// Round 2
// 818.781 us; speedup vs baseline: 1.3991x; 1.3991x over previous
//
#include <hip/hip_runtime.h>
#include <hip/hip_bf16.h>
#include <cstdint>
#include <cstddef>

// Problem constants (fixed by the harness problem instance).
#define MM 8192
#define KK 4096
#define NN 12288

typedef __bf16 bf16x8 __attribute__((ext_vector_type(8)));
typedef float  f32x4  __attribute__((ext_vector_type(4)));

// fp32 -> bf16 round-to-nearest-even (finite inputs).
__device__ __forceinline__ unsigned short f2bf(float f) {
    union { float f; unsigned int u; } v; v.f = f;
    unsigned int r = v.u + 0x7fffu + ((v.u >> 16) & 1u);
    return (unsigned short)(r >> 16);
}

// async global->LDS, 16 B per lane. LDS dest is wave-uniform base + lane*16.
__device__ __forceinline__ void gload_lds16(const void* g, void* l) {
    __builtin_amdgcn_global_load_lds(
        (__attribute__((address_space(1))) void*)g,
        (__attribute__((address_space(3))) void*)l,
        16, 0, 0);
}

#define FENCE() asm volatile("" ::: "memory")
#define LGKM0() asm volatile("s_waitcnt lgkmcnt(0)" ::: "memory")
#define BARF()  do { FENCE(); __builtin_amdgcn_s_barrier(); FENCE(); } while (0)

// ---------------- pre-pass 1: input fp32 -> bf16 ----------------
__global__ __launch_bounds__(256) void cvt_a_kernel(
    const float* __restrict__ in, unsigned short* __restrict__ out)
{
    size_t i = (size_t)blockIdx.x * 256 + threadIdx.x;   // 8 elems / thread
    const float4* p = (const float4*)in;
    float4 x = p[2 * i], y = p[2 * i + 1];
    union { unsigned short h[8]; uint4 v; } u;
    u.h[0] = f2bf(x.x); u.h[1] = f2bf(x.y); u.h[2] = f2bf(x.z); u.h[3] = f2bf(x.w);
    u.h[4] = f2bf(y.x); u.h[5] = f2bf(y.y); u.h[6] = f2bf(y.z); u.h[7] = f2bf(y.w);
    ((uint4*)out)[i] = u.v;
}

// ---------------- pre-pass 2: dequant int4 codes -> bf16 [N,K] ----------------
__global__ __launch_bounds__(256) void dq_w_kernel(
    const int* __restrict__ w, const float* __restrict__ snz,
    unsigned short* __restrict__ out)
{
    size_t t = (size_t)blockIdx.x * 256 + threadIdx.x;   // 8 codes / thread
    int kc = (int)(t & (KK / 8 - 1));                    // K/8 = 512
    int n  = (int)(t >> 9);
    int g  = kc >> 2;                                    // 32 codes per group
    float2 sz = ((const float2*)snz)[(size_t)g * NN + n];  // {scale, zero}
    const int4* wp = (const int4*)w;
    int4 q0 = wp[2 * t], q1 = wp[2 * t + 1];
    union { unsigned short h[8]; uint4 v; } u;
    u.h[0] = f2bf((float)(q0.x - 8) * sz.x + sz.y);
    u.h[1] = f2bf((float)(q0.y - 8) * sz.x + sz.y);
    u.h[2] = f2bf((float)(q0.z - 8) * sz.x + sz.y);
    u.h[3] = f2bf((float)(q0.w - 8) * sz.x + sz.y);
    u.h[4] = f2bf((float)(q1.x - 8) * sz.x + sz.y);
    u.h[5] = f2bf((float)(q1.y - 8) * sz.x + sz.y);
    u.h[6] = f2bf((float)(q1.z - 8) * sz.x + sz.y);
    u.h[7] = f2bf((float)(q1.w - 8) * sz.x + sz.y);
    ((uint4*)out)[t] = u.v;
}

// ================= 256x256 8-phase GEMM (T2+T3+T4+T5) =================
// C[M,N] = A[M,K](bf16) * W[N,K](bf16)^T + bias, fp32 out.
// 8 waves (2M x 4N), wave output 128x64, acc[8][4] f32x4.
// LDS 128 KiB = 2 K-tile buffers, each {A:256x64, B:256x64} bf16, 128 B rows,
// chunk-XOR swizzle (phys_chunk = logical ^ (row&7)) on both write-source and read.
// Per K-tile: 4 phases. Stage schedule (1 half-tile = 128 rows = 2 gload_lds/thread):
//   p0: stage B-half0(t+1)->other buf   p1: stage B-half1(t+1)->other buf
//   p2: stage A-half0(t+2)->CURRENT buf p3: stage A-half1(t+2)->current buf
// In-place A restage is safe: all A reads of tile t complete before p1's
// lgkmcnt(0)+barrier; stages issue after that barrier. B regions free after p3.
// Boundary (end of p3): vmcnt(4) (= the 2 A-halves of t+2 still in flight),
// vmcnt(0) only entering the last tile. Never drains in steady state.
#define BM 256
#define BN 256
#define BK 64
#define TT (KK / BK)   // 64

__global__ __launch_bounds__(512, 2) void gemm256_kernel(
    const unsigned short* __restrict__ A,    // bf16 [M,K]
    const unsigned short* __restrict__ Bw,   // bf16 [N,K]
    const float* __restrict__ bias,          // [N]
    float* __restrict__ C)                   // fp32 [M,N]
{
    __shared__ char lds[131072];

    const int tid  = threadIdx.x;
    const int lane = tid & 63;
    const int wave = tid >> 6;            // 0..7
    const int wm   = wave >> 2;           // 0..1
    const int wn   = wave & 3;            // 0..3

    // XCD-aware swizzle (nwg = 32*48 = 1536, divisible by 8).
    const int NTN = NN / BN;              // 48
    const int nwg = (MM / BM) * NTN;      // 1536
    const int cpx = nwg >> 3;             // 192
    int wg = ((int)blockIdx.x & 7) * cpx + ((int)blockIdx.x >> 3);
    const int tm = wg / NTN;
    const int tn = wg - tm * NTN;

    f32x4 acc[8][4] = {};

    // ---- staging lane constants ----
    // wave writes a 1-KiB block per gload_lds: rows wave*8+(lane>>3) (+64 for
    // second issue), phys chunk lane&7 holding logical (lane&7)^(row&7).
    const int lrow = lane >> 3;
    const int lc   = (lane & 7) ^ lrow;
    const unsigned short* aSrc = A  + (size_t)(tm * BM + wave * 8 + lrow) * KK + lc * 8;
    const unsigned short* bSrc = Bw + (size_t)(tn * BN + wave * 8 + lrow) * KK + lc * 8;
    const int wblk = wave * 1024;

#define STAGE(srcBase, rowsOff, kOff, ldsOff) do {                                     \
        gload_lds16((srcBase) + (size_t)(rowsOff) * KK + (kOff), lds + (ldsOff) + wblk);            \
        gload_lds16((srcBase) + (size_t)((rowsOff) + 64) * KK + (kOff), lds + (ldsOff) + 8192 + wblk); \
    } while (0)

    // ---- compute lane constants ----
    const int r7  = lane & 7;
    const int l15 = lane & 15;
    const int c0  = (((lane >> 4)    ) ^ r7) * 16;   // kk0 phys chunk byte
    const int c1  = (((lane >> 4) + 4) ^ r7) * 16;   // kk1 phys chunk byte
    const int aoff = (wm * 128 + l15) * 128;         // A row byte offset
    const int boff = (wn * 64  + l15) * 128;         // B row byte offset (nf adds 2048)

    // ---- prologue: tile0 {A0,A1,B0,B1} -> buf0; tile1 {A0,A1} -> buf1 ----
    STAGE(aSrc, 0,   0, 0);
    STAGE(aSrc, 128, 0, 16384);
    STAGE(bSrc, 0,   0, 32768);
    STAGE(bSrc, 128, 0, 32768 + 16384);
    if (TT > 1) {
        STAGE(aSrc, 0,   BK, 65536);
        STAGE(aSrc, 128, BK, 65536 + 16384);
    }
    asm volatile("s_waitcnt vmcnt(4)" ::: "memory");   // tile0 fully landed
    BARF();

#pragma unroll 2
    for (int t = 0; t < TT; ++t) {
        const int cb = t & 1, nb = cb ^ 1;
        const char* Ab = lds + cb * 65536;
        const char* Bb = lds + cb * 65536 + 32768;

        // ---- phase 0: read A-kk0(8) + B n0,n1 kk0(2); stage B-half0(t+1) ----
        bf16x8 a0[8];
#pragma unroll
        for (int mf = 0; mf < 8; ++mf)
            a0[mf] = *(const bf16x8*)(Ab + aoff + mf * 2048 + c0);
        bf16x8 p0b0 = *(const bf16x8*)(Bb + boff + 0 * 2048 + c0);
        bf16x8 p0b1 = *(const bf16x8*)(Bb + boff + 1 * 2048 + c0);
        if (t + 1 < TT) STAGE(bSrc, 0, (t + 1) * BK, nb * 65536 + 32768);
        BARF(); LGKM0();
        __builtin_amdgcn_s_setprio(1);
#pragma unroll
        for (int mf = 0; mf < 8; ++mf) {
            acc[mf][0] = __builtin_amdgcn_mfma_f32_16x16x32_bf16(a0[mf], p0b0, acc[mf][0], 0, 0, 0);
            acc[mf][1] = __builtin_amdgcn_mfma_f32_16x16x32_bf16(a0[mf], p0b1, acc[mf][1], 0, 0, 0);
        }
        __builtin_amdgcn_s_setprio(0);
        BARF();

        // ---- phase 1: read A-kk1(8) + B n2,n3 kk0(2); stage B-half1(t+1) ----
        bf16x8 a1[8];
#pragma unroll
        for (int mf = 0; mf < 8; ++mf)
            a1[mf] = *(const bf16x8*)(Ab + aoff + mf * 2048 + c1);
        bf16x8 p1b2 = *(const bf16x8*)(Bb + boff + 2 * 2048 + c0);
        bf16x8 p1b3 = *(const bf16x8*)(Bb + boff + 3 * 2048 + c0);
        if (t + 1 < TT) STAGE(bSrc, 128, (t + 1) * BK, nb * 65536 + 32768 + 16384);
        BARF(); LGKM0();
        __builtin_amdgcn_s_setprio(1);
#pragma unroll
        for (int mf = 0; mf < 8; ++mf) {
            acc[mf][2] = __builtin_amdgcn_mfma_f32_16x16x32_bf16(a0[mf], p1b2, acc[mf][2], 0, 0, 0);
            acc[mf][3] = __builtin_amdgcn_mfma_f32_16x16x32_bf16(a0[mf], p1b3, acc[mf][3], 0, 0, 0);
        }
        __builtin_amdgcn_s_setprio(0);
        BARF();

        // ---- phase 2: read B n0,n1 kk1(2); stage A-half0(t+2) into CURRENT buf ----
        bf16x8 p2b0 = *(const bf16x8*)(Bb + boff + 0 * 2048 + c1);
        bf16x8 p2b1 = *(const bf16x8*)(Bb + boff + 1 * 2048 + c1);
        if (t + 2 < TT) STAGE(aSrc, 0, (t + 2) * BK, cb * 65536);
        BARF(); LGKM0();
        __builtin_amdgcn_s_setprio(1);
#pragma unroll
        for (int mf = 0; mf < 8; ++mf) {
            acc[mf][0] = __builtin_amdgcn_mfma_f32_16x16x32_bf16(a1[mf], p2b0, acc[mf][0], 0, 0, 0);
            acc[mf][1] = __builtin_amdgcn_mfma_f32_16x16x32_bf16(a1[mf], p2b1, acc[mf][1], 0, 0, 0);
        }
        __builtin_amdgcn_s_setprio(0);
        BARF();

        // ---- phase 3: read B n2,n3 kk1(2); stage A-half1(t+2); boundary ----
        bf16x8 p3b2 = *(const bf16x8*)(Bb + boff + 2 * 2048 + c1);
        bf16x8 p3b3 = *(const bf16x8*)(Bb + boff + 3 * 2048 + c1);
        if (t + 2 < TT) STAGE(aSrc, 128, (t + 2) * BK, cb * 65536 + 16384);
        BARF(); LGKM0();
        __builtin_amdgcn_s_setprio(1);
#pragma unroll
        for (int mf = 0; mf < 8; ++mf) {
            acc[mf][2] = __builtin_amdgcn_mfma_f32_16x16x32_bf16(a1[mf], p3b2, acc[mf][2], 0, 0, 0);
            acc[mf][3] = __builtin_amdgcn_mfma_f32_16x16x32_bf16(a1[mf], p3b3, acc[mf][3], 0, 0, 0);
        }
        __builtin_amdgcn_s_setprio(0);
        if (t < TT - 1) {
            if (t + 2 < TT) { asm volatile("s_waitcnt vmcnt(4)" ::: "memory"); }
            else            { asm volatile("s_waitcnt vmcnt(0)" ::: "memory"); }
            BARF();
        }
    }
#undef STAGE

    // ---- epilogue: C/D layout col=lane&15, row=(lane>>4)*4+j; fuse bias ----
    const int crow = tm * BM + wm * 128 + (lane >> 4) * 4;
    const int ccol = tn * BN + wn * 64 + l15;
    float bv[4];
#pragma unroll
    for (int nf = 0; nf < 4; ++nf) bv[nf] = bias[ccol + nf * 16];
#pragma unroll
    for (int mf = 0; mf < 8; ++mf)
#pragma unroll
        for (int nf = 0; nf < 4; ++nf)
#pragma unroll
            for (int j = 0; j < 4; ++j)
                C[(size_t)(crow + mf * 16 + j) * NN + ccol + nf * 16] =
                    acc[mf][nf][j] + bv[nf];
}

// ================= fallback: fused 128x128 (R1, known-correct) =================
__global__ __launch_bounds__(256) void gemm_fused_kernel(
    const float* __restrict__ Af,
    const int* __restrict__ Wq,
    const float* __restrict__ snz,
    const float* __restrict__ bias,
    float* __restrict__ C)
{
    __shared__ alignas(16) unsigned short As[128 * 64];
    __shared__ alignas(16) unsigned short Bs[128 * 64];

    const int tid  = threadIdx.x;
    const int lane = tid & 63;
    const int wave = tid >> 6;

    const int NTN = NN / 128;
    const int nwg = (MM / 128) * NTN;
    const int cpx = nwg >> 3;
    int wg = ((int)blockIdx.x & 7) * cpx + ((int)blockIdx.x >> 3);
    const int tm = wg / NTN;
    const int tn = wg - tm * NTN;

    const int wm = wave >> 1, wn = wave & 1;

    f32x4 acc[4][4] = {};

    const int r7  = lane & 7;
    const int pc0 = (((lane >> 4)    ) ^ r7) * 16;
    const int pc1 = (((lane >> 4) + 4) ^ r7) * 16;
    const int arow = wm * 64 + (lane & 15);
    const int brow = wn * 64 + (lane & 15);
    const char* AsR = (const char*)As;
    const char* BsR = (const char*)Bs;

    const int frow = tid >> 1;
    const int fh   = tid & 1;
    const int frx  = frow & 7;

    for (int k0 = 0; k0 < KK; k0 += 64) {
        {
            const float* ap = Af + (size_t)(tm * 128 + frow) * KK + k0 + fh * 32;
#pragma unroll
            for (int c = 0; c < 4; ++c) {
                float4 x = ((const float4*)ap)[2 * c];
                float4 y = ((const float4*)ap)[2 * c + 1];
                union { unsigned short h[8]; uint4 v; } u;
                u.h[0] = f2bf(x.x); u.h[1] = f2bf(x.y); u.h[2] = f2bf(x.z); u.h[3] = f2bf(x.w);
                u.h[4] = f2bf(y.x); u.h[5] = f2bf(y.y); u.h[6] = f2bf(y.z); u.h[7] = f2bf(y.w);
                int lc2 = fh * 4 + c;
                *(uint4*)&As[frow * 64 + ((lc2 ^ frx) * 8)] = u.v;
            }
        }
        {
            const int nrow = tn * 128 + frow;
            const int* wp = Wq + (size_t)nrow * KK + k0 + fh * 32;
            float2 sz = ((const float2*)snz)[(size_t)((k0 >> 5) + fh) * NN + nrow];
#pragma unroll
            for (int c = 0; c < 4; ++c) {
                int4 q0 = ((const int4*)wp)[2 * c];
                int4 q1 = ((const int4*)wp)[2 * c + 1];
                union { unsigned short h[8]; uint4 v; } u;
                u.h[0] = f2bf((float)(q0.x - 8) * sz.x + sz.y);
                u.h[1] = f2bf((float)(q0.y - 8) * sz.x + sz.y);
                u.h[2] = f2bf((float)(q0.z - 8) * sz.x + sz.y);
                u.h[3] = f2bf((float)(q0.w - 8) * sz.x + sz.y);
                u.h[4] = f2bf((float)(q1.x - 8) * sz.x + sz.y);
                u.h[5] = f2bf((float)(q1.y - 8) * sz.x + sz.y);
                u.h[6] = f2bf((float)(q1.z - 8) * sz.x + sz.y);
                u.h[7] = f2bf((float)(q1.w - 8) * sz.x + sz.y);
                int lc2 = fh * 4 + c;
                *(uint4*)&Bs[frow * 64 + ((lc2 ^ frx) * 8)] = u.v;
            }
        }
        __syncthreads();
        {
            bf16x8 af[4], bfr[4];
#pragma unroll
            for (int x = 0; x < 4; ++x) {
                af[x]  = *(const bf16x8*)(AsR + (arow + x * 16) * 128 + pc0);
                bfr[x] = *(const bf16x8*)(BsR + (brow + x * 16) * 128 + pc0);
            }
#pragma unroll
            for (int mi = 0; mi < 4; ++mi)
#pragma unroll
                for (int ni = 0; ni < 4; ++ni)
                    acc[mi][ni] = __builtin_amdgcn_mfma_f32_16x16x32_bf16(
                        af[mi], bfr[ni], acc[mi][ni], 0, 0, 0);
        }
        {
            bf16x8 af[4], bfr[4];
#pragma unroll
            for (int x = 0; x < 4; ++x) {
                af[x]  = *(const bf16x8*)(AsR + (arow + x * 16) * 128 + pc1);
                bfr[x] = *(const bf16x8*)(BsR + (brow + x * 16) * 128 + pc1);
            }
#pragma unroll
            for (int mi = 0; mi < 4; ++mi)
#pragma unroll
                for (int ni = 0; ni < 4; ++ni)
                    acc[mi][ni] = __builtin_amdgcn_mfma_f32_16x16x32_bf16(
                        af[mi], bfr[ni], acc[mi][ni], 0, 0, 0);
        }
        __syncthreads();
    }

    const int crow = tm * 128 + wm * 64 + (lane >> 4) * 4;
    const int ccol = tn * 128 + wn * 64 + (lane & 15);
    float bv[4];
#pragma unroll
    for (int ni = 0; ni < 4; ++ni) bv[ni] = bias[ccol + ni * 16];
#pragma unroll
    for (int mi = 0; mi < 4; ++mi)
#pragma unroll
        for (int ni = 0; ni < 4; ++ni)
#pragma unroll
            for (int j = 0; j < 4; ++j)
                C[(size_t)(crow + mi * 16 + j) * NN + ccol + ni * 16] =
                    acc[mi][ni][j] + bv[ni];
}

extern "C" void kernel_launch(void* const* d_in, const int* in_sizes, int n_in,
                              void* d_out, int out_size, void* d_ws, size_t ws_size,
                              hipStream_t stream)
{
    const float* inA  = (const float*)d_in[0];   // [M,K] fp32
    const int*   Wq   = (const int*)d_in[1];     // [N,K] int codes
    const float* snz  = (const float*)d_in[2];   // [K/32,N,2] fp32
    const float* bias = (const float*)d_in[3];   // [N] fp32
    float* out = (float*)d_out;

    const size_t needA = (size_t)MM * KK * 2;
    const size_t needW = (size_t)NN * KK * 2;

    if (ws_size >= needA + needW) {
        unsigned short* Abf = (unsigned short*)d_ws;
        unsigned short* Wbf = (unsigned short*)((char*)d_ws + needA);
        cvt_a_kernel<<<(MM * KK / 8) / 256, 256, 0, stream>>>(inA, Abf);
        dq_w_kernel<<<(NN * KK / 8) / 256, 256, 0, stream>>>(Wq, snz, Wbf);
        gemm256_kernel<<<(MM / BM) * (NN / BN), 512, 0, stream>>>(Abf, Wbf, bias, out);
    } else {
        gemm_fused_kernel<<<(MM / 128) * (NN / 128), 256, 0, stream>>>(
            inA, Wq, snz, bias, out);
    }
}

// Round 3
// 817.713 us; speedup vs baseline: 1.4009x; 1.0013x over previous
//
#include <hip/hip_runtime.h>
#include <hip/hip_bf16.h>
#include <cstdint>
#include <cstddef>

// Problem constants (fixed by the harness problem instance).
#define MM 8192
#define KK 4096
#define NN 12288

typedef __bf16 bf16x8 __attribute__((ext_vector_type(8)));
typedef float  f32x4  __attribute__((ext_vector_type(4)));

// fp32 -> bf16 round-to-nearest-even (finite inputs).
__device__ __forceinline__ unsigned short f2bf(float f) {
    union { float f; unsigned int u; } v; v.f = f;
    unsigned int r = v.u + 0x7fffu + ((v.u >> 16) & 1u);
    return (unsigned short)(r >> 16);
}

// async global->LDS, 16 B per lane. LDS dest is wave-uniform base + lane*16.
__device__ __forceinline__ void gload_lds16(const void* g, void* l) {
    __builtin_amdgcn_global_load_lds(
        (__attribute__((address_space(1))) void*)g,
        (__attribute__((address_space(3))) void*)l,
        16, 0, 0);
}

#define FENCE() asm volatile("" ::: "memory")
#define LGKM0() asm volatile("s_waitcnt lgkmcnt(0)" ::: "memory")
#define BARF()  do { FENCE(); __builtin_amdgcn_s_barrier(); FENCE(); } while (0)

// ---------------- pre-pass 1: input fp32 -> bf16 ----------------
__global__ __launch_bounds__(256) void cvt_a_kernel(
    const float* __restrict__ in, unsigned short* __restrict__ out)
{
    size_t i = (size_t)blockIdx.x * 256 + threadIdx.x;   // 8 elems / thread
    const float4* p = (const float4*)in;
    float4 x = p[2 * i], y = p[2 * i + 1];
    union { unsigned short h[8]; uint4 v; } u;
    u.h[0] = f2bf(x.x); u.h[1] = f2bf(x.y); u.h[2] = f2bf(x.z); u.h[3] = f2bf(x.w);
    u.h[4] = f2bf(y.x); u.h[5] = f2bf(y.y); u.h[6] = f2bf(y.z); u.h[7] = f2bf(y.w);
    ((uint4*)out)[i] = u.v;
}

// ---------------- pre-pass 2: dequant int4 codes -> bf16 [N,K] ----------------
__global__ __launch_bounds__(256) void dq_w_kernel(
    const int* __restrict__ w, const float* __restrict__ snz,
    unsigned short* __restrict__ out)
{
    size_t t = (size_t)blockIdx.x * 256 + threadIdx.x;   // 8 codes / thread
    int kc = (int)(t & (KK / 8 - 1));                    // K/8 = 512
    int n  = (int)(t >> 9);
    int g  = kc >> 2;                                    // 32 codes per group
    float2 sz = ((const float2*)snz)[(size_t)g * NN + n];  // {scale, zero}
    const int4* wp = (const int4*)w;
    int4 q0 = wp[2 * t], q1 = wp[2 * t + 1];
    union { unsigned short h[8]; uint4 v; } u;
    u.h[0] = f2bf((float)(q0.x - 8) * sz.x + sz.y);
    u.h[1] = f2bf((float)(q0.y - 8) * sz.x + sz.y);
    u.h[2] = f2bf((float)(q0.z - 8) * sz.x + sz.y);
    u.h[3] = f2bf((float)(q0.w - 8) * sz.x + sz.y);
    u.h[4] = f2bf((float)(q1.x - 8) * sz.x + sz.y);
    u.h[5] = f2bf((float)(q1.y - 8) * sz.x + sz.y);
    u.h[6] = f2bf((float)(q1.z - 8) * sz.x + sz.y);
    u.h[7] = f2bf((float)(q1.w - 8) * sz.x + sz.y);
    ((uint4*)out)[t] = u.v;
}

// ================= 256x256 8-phase GEMM, deep pipeline =================
// C[M,N] = A[M,K](bf16) * W[N,K](bf16)^T + bias, fp32 out.
// 8 waves (2M x 4N), wave output 128x64, acc[8][4] f32x4.
// LDS 160 KiB: A double-buffered (2 x 32 KiB @ 0/32768),
//              B TRIPLE-buffered (3 x 32 KiB @ 65536 + i*32768).
// 128-B rows, chunk-XOR swizzle (phys_chunk = logical ^ (row&7)) on both
// write-source and read side. Per K-tile: 4 phases {ds_reads; stage; barrier;
// lgkmcnt(0); setprio(1); 16 MFMA; setprio(0); barrier}.
// Stage schedule: tile t stages B(t+2)->Bbuf[(t+2)%3] at p0/p1 (that buffer
// held B(t-1), last read at p3 of t-1) and A(t+2)->Abuf[t&1] in-place at
// p2/p3 (A(t) last read at p1; all waves' reads drained by p1's
// lgkmcnt(0)+closing barrier).
// Boundary: vmcnt(8) -> ALL 4 half-tiles of t+2 (8 loads) stay in flight;
// everything older (tile t+1's data, staged during t-1) is guaranteed landed.
// vmcnt(0) only entering the last tile. ~8 phases (~1600 cy) of latency cover.
#define BM 256
#define BN 256
#define BK 64
#define TT (KK / BK)   // 64

__global__ __launch_bounds__(512, 2) void gemm256_kernel(
    const unsigned short* __restrict__ A,    // bf16 [M,K]
    const unsigned short* __restrict__ Bw,   // bf16 [N,K]
    const float* __restrict__ bias,          // [N]
    float* __restrict__ C)                   // fp32 [M,N]
{
    __shared__ char lds[163840];

    const int tid  = threadIdx.x;
    const int lane = tid & 63;
    const int wave = tid >> 6;            // 0..7
    const int wm   = wave >> 2;           // 0..1
    const int wn   = wave & 3;            // 0..3

    // XCD-aware swizzle (nwg = 32*48 = 1536, divisible by 8).
    const int NTN = NN / BN;              // 48
    const int nwg = (MM / BM) * NTN;      // 1536
    const int cpx = nwg >> 3;             // 192
    int wg = ((int)blockIdx.x & 7) * cpx + ((int)blockIdx.x >> 3);
    const int tm = wg / NTN;
    const int tn = wg - tm * NTN;

    f32x4 acc[8][4] = {};

    // ---- staging lane constants ----
    // wave writes a 1-KiB block per gload_lds: rows (base + wave*8 + lane>>3),
    // phys chunk lane&7 holding logical (lane&7)^(row&7).
    const int lrow = lane >> 3;
    const int lc   = (lane & 7) ^ lrow;
    const unsigned short* aSrc = A  + (size_t)(tm * BM + wave * 8 + lrow) * KK + lc * 8;
    const unsigned short* bSrc = Bw + (size_t)(tn * BN + wave * 8 + lrow) * KK + lc * 8;
    const int wblk = wave * 1024;

    // half-tile stage: 2 gload_lds, covers 128 rows x 64 bf16 = 16 KiB.
#define STAGE(srcBase, rowsOff, kOff, ldsPtr) do {                                          \
        gload_lds16((srcBase) + (size_t)(rowsOff) * KK + (kOff), (ldsPtr) + wblk);          \
        gload_lds16((srcBase) + (size_t)((rowsOff) + 64) * KK + (kOff), (ldsPtr) + 8192 + wblk); \
    } while (0)

    // ---- compute lane constants ----
    const int r7  = lane & 7;
    const int l15 = lane & 15;
    const int c0  = (((lane >> 4)    ) ^ r7) * 16;   // kk0 phys chunk byte
    const int c1  = (((lane >> 4) + 4) ^ r7) * 16;   // kk1 phys chunk byte
    const int aoff = (wm * 128 + l15) * 128;         // A row byte offset (mf adds 2048)
    const int boff = (wn * 64  + l15) * 128;         // B row byte offset (nf adds 2048)

    // ---- prologue ----
    // Order matters: tile0 first (oldest 8), then tile1; vmcnt(8) => tile0 landed,
    // tile1's 8 loads in flight (covered by tile0's boundary vmcnt(8)).
    STAGE(aSrc, 0,   0, lds + 0);
    STAGE(aSrc, 128, 0, lds + 16384);
    STAGE(bSrc, 0,   0, lds + 65536);
    STAGE(bSrc, 128, 0, lds + 65536 + 16384);
    STAGE(aSrc, 0,   BK, lds + 32768);
    STAGE(aSrc, 128, BK, lds + 32768 + 16384);
    STAGE(bSrc, 0,   BK, lds + 65536 + 32768);
    STAGE(bSrc, 128, BK, lds + 65536 + 32768 + 16384);
    asm volatile("s_waitcnt vmcnt(8)" ::: "memory");
    BARF();

    int bRead = 0;   // t % 3
    for (int t = 0; t < TT; ++t) {
        const char* Ab = lds + ((t & 1) << 15);
        const char* Bb = lds + 65536 + (bRead << 15);
        int bs = bRead + 2; if (bs >= 3) bs -= 3;     // (t+2) % 3
        char* Bst = lds + 65536 + (bs << 15);
        char* Ast = lds + ((t & 1) << 15);            // in-place A restage
        const bool pf = (t + 2 < TT);
        const int kpf = (t + 2) * BK;

        // ---- phase 0: read A-kk0(8) + B n0,n1 kk0(2); stage B-h0(t+2) ----
        bf16x8 a0[8];
#pragma unroll
        for (int mf = 0; mf < 8; ++mf)
            a0[mf] = *(const bf16x8*)(Ab + aoff + mf * 2048 + c0);
        bf16x8 p0b0 = *(const bf16x8*)(Bb + boff + 0 * 2048 + c0);
        bf16x8 p0b1 = *(const bf16x8*)(Bb + boff + 1 * 2048 + c0);
        if (pf) STAGE(bSrc, 0, kpf, Bst);
        BARF(); LGKM0();
        __builtin_amdgcn_s_setprio(1);
#pragma unroll
        for (int mf = 0; mf < 8; ++mf) {
            acc[mf][0] = __builtin_amdgcn_mfma_f32_16x16x32_bf16(a0[mf], p0b0, acc[mf][0], 0, 0, 0);
            acc[mf][1] = __builtin_amdgcn_mfma_f32_16x16x32_bf16(a0[mf], p0b1, acc[mf][1], 0, 0, 0);
        }
        __builtin_amdgcn_s_setprio(0);
        BARF();

        // ---- phase 1: read A-kk1(8) + B n2,n3 kk0(2); stage B-h1(t+2) ----
        bf16x8 a1[8];
#pragma unroll
        for (int mf = 0; mf < 8; ++mf)
            a1[mf] = *(const bf16x8*)(Ab + aoff + mf * 2048 + c1);
        bf16x8 p1b2 = *(const bf16x8*)(Bb + boff + 2 * 2048 + c0);
        bf16x8 p1b3 = *(const bf16x8*)(Bb + boff + 3 * 2048 + c0);
        if (pf) STAGE(bSrc, 128, kpf, Bst + 16384);
        BARF(); LGKM0();
        __builtin_amdgcn_s_setprio(1);
#pragma unroll
        for (int mf = 0; mf < 8; ++mf) {
            acc[mf][2] = __builtin_amdgcn_mfma_f32_16x16x32_bf16(a0[mf], p1b2, acc[mf][2], 0, 0, 0);
            acc[mf][3] = __builtin_amdgcn_mfma_f32_16x16x32_bf16(a0[mf], p1b3, acc[mf][3], 0, 0, 0);
        }
        __builtin_amdgcn_s_setprio(0);
        BARF();

        // ---- phase 2: read B n0,n1 kk1(2); stage A-h0(t+2) in place ----
        bf16x8 p2b0 = *(const bf16x8*)(Bb + boff + 0 * 2048 + c1);
        bf16x8 p2b1 = *(const bf16x8*)(Bb + boff + 1 * 2048 + c1);
        if (pf) STAGE(aSrc, 0, kpf, Ast);
        BARF(); LGKM0();
        __builtin_amdgcn_s_setprio(1);
#pragma unroll
        for (int mf = 0; mf < 8; ++mf) {
            acc[mf][0] = __builtin_amdgcn_mfma_f32_16x16x32_bf16(a1[mf], p2b0, acc[mf][0], 0, 0, 0);
            acc[mf][1] = __builtin_amdgcn_mfma_f32_16x16x32_bf16(a1[mf], p2b1, acc[mf][1], 0, 0, 0);
        }
        __builtin_amdgcn_s_setprio(0);
        BARF();

        // ---- phase 3: read B n2,n3 kk1(2); stage A-h1(t+2); boundary ----
        bf16x8 p3b2 = *(const bf16x8*)(Bb + boff + 2 * 2048 + c1);
        bf16x8 p3b3 = *(const bf16x8*)(Bb + boff + 3 * 2048 + c1);
        if (pf) STAGE(aSrc, 128, kpf, Ast + 16384);
        BARF(); LGKM0();
        __builtin_amdgcn_s_setprio(1);
#pragma unroll
        for (int mf = 0; mf < 8; ++mf) {
            acc[mf][2] = __builtin_amdgcn_mfma_f32_16x16x32_bf16(a1[mf], p3b2, acc[mf][2], 0, 0, 0);
            acc[mf][3] = __builtin_amdgcn_mfma_f32_16x16x32_bf16(a1[mf], p3b3, acc[mf][3], 0, 0, 0);
        }
        __builtin_amdgcn_s_setprio(0);
        if (t < TT - 1) {
            if (pf) { asm volatile("s_waitcnt vmcnt(8)" ::: "memory"); }
            else    { asm volatile("s_waitcnt vmcnt(0)" ::: "memory"); }
            BARF();
        }
        bRead = bRead + 1; if (bRead >= 3) bRead -= 3;
    }
#undef STAGE

    // ---- epilogue: C/D layout col=lane&15, row=(lane>>4)*4+j; fuse bias ----
    const int crow = tm * BM + wm * 128 + (lane >> 4) * 4;
    const int ccol = tn * BN + wn * 64 + l15;
    float bv[4];
#pragma unroll
    for (int nf = 0; nf < 4; ++nf) bv[nf] = bias[ccol + nf * 16];
#pragma unroll
    for (int mf = 0; mf < 8; ++mf)
#pragma unroll
        for (int nf = 0; nf < 4; ++nf)
#pragma unroll
            for (int j = 0; j < 4; ++j)
                C[(size_t)(crow + mf * 16 + j) * NN + ccol + nf * 16] =
                    acc[mf][nf][j] + bv[nf];
}

// ================= fallback: fused 128x128 (R1, known-correct) =================
__global__ __launch_bounds__(256) void gemm_fused_kernel(
    const float* __restrict__ Af,
    const int* __restrict__ Wq,
    const float* __restrict__ snz,
    const float* __restrict__ bias,
    float* __restrict__ C)
{
    __shared__ alignas(16) unsigned short As[128 * 64];
    __shared__ alignas(16) unsigned short Bs[128 * 64];

    const int tid  = threadIdx.x;
    const int lane = tid & 63;
    const int wave = tid >> 6;

    const int NTN = NN / 128;
    const int nwg = (MM / 128) * NTN;
    const int cpx = nwg >> 3;
    int wg = ((int)blockIdx.x & 7) * cpx + ((int)blockIdx.x >> 3);
    const int tm = wg / NTN;
    const int tn = wg - tm * NTN;

    const int wm = wave >> 1, wn = wave & 1;

    f32x4 acc[4][4] = {};

    const int r7  = lane & 7;
    const int pc0 = (((lane >> 4)    ) ^ r7) * 16;
    const int pc1 = (((lane >> 4) + 4) ^ r7) * 16;
    const int arow = wm * 64 + (lane & 15);
    const int brow = wn * 64 + (lane & 15);
    const char* AsR = (const char*)As;
    const char* BsR = (const char*)Bs;

    const int frow = tid >> 1;
    const int fh   = tid & 1;
    const int frx  = frow & 7;

    for (int k0 = 0; k0 < KK; k0 += 64) {
        {
            const float* ap = Af + (size_t)(tm * 128 + frow) * KK + k0 + fh * 32;
#pragma unroll
            for (int c = 0; c < 4; ++c) {
                float4 x = ((const float4*)ap)[2 * c];
                float4 y = ((const float4*)ap)[2 * c + 1];
                union { unsigned short h[8]; uint4 v; } u;
                u.h[0] = f2bf(x.x); u.h[1] = f2bf(x.y); u.h[2] = f2bf(x.z); u.h[3] = f2bf(x.w);
                u.h[4] = f2bf(y.x); u.h[5] = f2bf(y.y); u.h[6] = f2bf(y.z); u.h[7] = f2bf(y.w);
                int lc2 = fh * 4 + c;
                *(uint4*)&As[frow * 64 + ((lc2 ^ frx) * 8)] = u.v;
            }
        }
        {
            const int nrow = tn * 128 + frow;
            const int* wp = Wq + (size_t)nrow * KK + k0 + fh * 32;
            float2 sz = ((const float2*)snz)[(size_t)((k0 >> 5) + fh) * NN + nrow];
#pragma unroll
            for (int c = 0; c < 4; ++c) {
                int4 q0 = ((const int4*)wp)[2 * c];
                int4 q1 = ((const int4*)wp)[2 * c + 1];
                union { unsigned short h[8]; uint4 v; } u;
                u.h[0] = f2bf((float)(q0.x - 8) * sz.x + sz.y);
                u.h[1] = f2bf((float)(q0.y - 8) * sz.x + sz.y);
                u.h[2] = f2bf((float)(q0.z - 8) * sz.x + sz.y);
                u.h[3] = f2bf((float)(q0.w - 8) * sz.x + sz.y);
                u.h[4] = f2bf((float)(q1.x - 8) * sz.x + sz.y);
                u.h[5] = f2bf((float)(q1.y - 8) * sz.x + sz.y);
                u.h[6] = f2bf((float)(q1.z - 8) * sz.x + sz.y);
                u.h[7] = f2bf((float)(q1.w - 8) * sz.x + sz.y);
                int lc2 = fh * 4 + c;
                *(uint4*)&Bs[frow * 64 + ((lc2 ^ frx) * 8)] = u.v;
            }
        }
        __syncthreads();
        {
            bf16x8 af[4], bfr[4];
#pragma unroll
            for (int x = 0; x < 4; ++x) {
                af[x]  = *(const bf16x8*)(AsR + (arow + x * 16) * 128 + pc0);
                bfr[x] = *(const bf16x8*)(BsR + (brow + x * 16) * 128 + pc0);
            }
#pragma unroll
            for (int mi = 0; mi < 4; ++mi)
#pragma unroll
                for (int ni = 0; ni < 4; ++ni)
                    acc[mi][ni] = __builtin_amdgcn_mfma_f32_16x16x32_bf16(
                        af[mi], bfr[ni], acc[mi][ni], 0, 0, 0);
        }
        {
            bf16x8 af[4], bfr[4];
#pragma unroll
            for (int x = 0; x < 4; ++x) {
                af[x]  = *(const bf16x8*)(AsR + (arow + x * 16) * 128 + pc1);
                bfr[x] = *(const bf16x8*)(BsR + (brow + x * 16) * 128 + pc1);
            }
#pragma unroll
            for (int mi = 0; mi < 4; ++mi)
#pragma unroll
                for (int ni = 0; ni < 4; ++ni)
                    acc[mi][ni] = __builtin_amdgcn_mfma_f32_16x16x32_bf16(
                        af[mi], bfr[ni], acc[mi][ni], 0, 0, 0);
        }
        __syncthreads();
    }

    const int crow = tm * 128 + wm * 64 + (lane >> 4) * 4;
    const int ccol = tn * 128 + wn * 64 + (lane & 15);
    float bv[4];
#pragma unroll
    for (int ni = 0; ni < 4; ++ni) bv[ni] = bias[ccol + ni * 16];
#pragma unroll
    for (int mi = 0; mi < 4; ++mi)
#pragma unroll
        for (int ni = 0; ni < 4; ++ni)
#pragma unroll
            for (int j = 0; j < 4; ++j)
                C[(size_t)(crow + mi * 16 + j) * NN + ccol + ni * 16] =
                    acc[mi][ni][j] + bv[ni];
}

extern "C" void kernel_launch(void* const* d_in, const int* in_sizes, int n_in,
                              void* d_out, int out_size, void* d_ws, size_t ws_size,
                              hipStream_t stream)
{
    const float* inA  = (const float*)d_in[0];   // [M,K] fp32
    const int*   Wq   = (const int*)d_in[1];     // [N,K] int codes
    const float* snz  = (const float*)d_in[2];   // [K/32,N,2] fp32
    const float* bias = (const float*)d_in[3];   // [N] fp32
    float* out = (float*)d_out;

    const size_t needA = (size_t)MM * KK * 2;
    const size_t needW = (size_t)NN * KK * 2;

    if (ws_size >= needA + needW) {
        unsigned short* Abf = (unsigned short*)d_ws;
        unsigned short* Wbf = (unsigned short*)((char*)d_ws + needA);
        cvt_a_kernel<<<(MM * KK / 8) / 256, 256, 0, stream>>>(inA, Abf);
        dq_w_kernel<<<(NN * KK / 8) / 256, 256, 0, stream>>>(Wq, snz, Wbf);
        gemm256_kernel<<<(MM / BM) * (NN / BN), 512, 0, stream>>>(Abf, Wbf, bias, out);
    } else {
        gemm_fused_kernel<<<(MM / 128) * (NN / 128), 256, 0, stream>>>(
            inA, Wq, snz, bias, out);
    }
}